// Round 2
// baseline (703.374 us; speedup 1.0000x reference)
//
#include <hip/hip_runtime.h>
#include <math.h>

typedef __bf16 bf16_t;
typedef __bf16 bf16x8 __attribute__((ext_vector_type(8)));
typedef __bf16 bf16x4 __attribute__((ext_vector_type(4)));
typedef float f32x4 __attribute__((ext_vector_type(4)));

#define MFMA16(a, b, c) __builtin_amdgcn_mfma_f32_16x16x32_bf16((a), (b), (c), 0, 0, 0)

// Problem constants
constexpr int Bc = 2, Nc = 2048, Dc = 1024, Hc = 16, HDc = 64;
constexpr float SCALE = 0.125f; // 1/sqrt(64)

// ---------------------------------------------------------------------------
// fp32 -> bf16 conversion, 4 elements/thread
__global__ __launch_bounds__(256) void f2b(const float* __restrict__ src,
                                           bf16_t* __restrict__ dst) {
    int i = (blockIdx.x * 256 + threadIdx.x) * 4;
    float4 v = *(const float4*)(src + i);
    bf16x4 o = { (bf16_t)v.x, (bf16_t)v.y, (bf16_t)v.z, (bf16_t)v.w };
    *(bf16x4*)(dst + i) = o;
}

// ---------------------------------------------------------------------------
// Transpose + convert: dst[c][r] = (bf16)src[r][c], R and C multiples of 64
__global__ __launch_bounds__(256) void tr64(const float* __restrict__ src,
                                            bf16_t* __restrict__ dst, int R, int C) {
    __shared__ bf16_t tile[64 * 66];
    int r0 = blockIdx.y * 64, c0 = blockIdx.x * 64;
    int t = threadIdx.x;
    int cl = t & 63, rl = t >> 6;
#pragma unroll
    for (int p = 0; p < 16; ++p) {
        int r = p * 4 + rl;
        tile[r * 66 + cl] = (bf16_t)src[(size_t)(r0 + r) * C + c0 + cl];
    }
    __syncthreads();
#pragma unroll
    for (int p = 0; p < 16; ++p) {
        int r = p * 4 + rl; // row in dst == column in src
        dst[(size_t)(c0 + r) * R + r0 + cl] = tile[cl * 66 + r];
    }
}

// ---------------------------------------------------------------------------
// Partial pooling: pooled[b][d] += sum over 64 rows (atomic f32). x is fp32.
__global__ __launch_bounds__(256) void pool_partial(const float* __restrict__ x,
                                                    float* __restrict__ pooled) {
    int blk = blockIdx.x;          // 64 blocks: b = blk>>5, chunk = blk&31
    int b = blk >> 5, ch = blk & 31;
    int t = threadIdx.x;
    int c = t * 4;
    float s0 = 0.f, s1 = 0.f, s2 = 0.f, s3 = 0.f;
    for (int rr = 0; rr < 64; ++rr) {
        float4 v = *(const float4*)(x + (size_t)(b * Nc + ch * 64 + rr) * Dc + c);
        s0 += v.x; s1 += v.y; s2 += v.z; s3 += v.w;
    }
    atomicAdd(&pooled[b * Dc + c + 0], s0);
    atomicAdd(&pooled[b * Dc + c + 1], s1);
    atomicAdd(&pooled[b * Dc + c + 2], s2);
    atomicAdd(&pooled[b * Dc + c + 3], s3);
}

// ---------------------------------------------------------------------------
// Gate: g[b] = sigmoid(silu(mean(x) @ w_fg1 + b_fg1) @ w_fg2 + b_fg2)  (fp32)
__global__ __launch_bounds__(256) void gate_k(const float* __restrict__ pooled,
                                              const float* __restrict__ w_fg1,
                                              const float* __restrict__ b_fg1,
                                              const float* __restrict__ w_fg2,
                                              const float* __restrict__ b_fg2,
                                              float* __restrict__ gbuf) {
    int b = blockIdx.x, j = threadIdx.x;
    const float inv_n = 1.0f / 2048.0f;
    float hj = b_fg1[j];
    for (int d = 0; d < 1024; ++d)
        hj += (pooled[b * 1024 + d] * inv_n) * w_fg1[d * 256 + j];
    hj = hj / (1.0f + __expf(-hj)); // silu
    __shared__ float red[256];
    red[j] = hj * w_fg2[j];
    __syncthreads();
    for (int s = 128; s > 0; s >>= 1) {
        if (j < s) red[j] += red[j + s];
        __syncthreads();
    }
    if (j == 0) {
        float z = red[0] + b_fg2[0];
        gbuf[b] = 1.0f / (1.0f + __expf(-z));
    }
}

// ---------------------------------------------------------------------------
// Coverage bias: biasbuf[b][h][n] = g[b] * (silu(cov*w_ce1+b_ce1) @ w_ce2 + b_ce2)
__global__ __launch_bounds__(256) void covbias_k(const float* __restrict__ coverage,
                                                 const float* __restrict__ w_ce1,
                                                 const float* __restrict__ b_ce1,
                                                 const float* __restrict__ w_ce2,
                                                 const float* __restrict__ b_ce2,
                                                 const float* __restrict__ gbuf,
                                                 float* __restrict__ biasbuf) {
    int t = threadIdx.x;
    int h = t & 15;
    int gn = blockIdx.x * 16 + (t >> 4); // 0..4095 over (b,n)
    int b = gn >> 11, n = gn & 2047;
    float c = coverage[gn];
    float acc = b_ce2[h];
    for (int j = 0; j < 256; ++j) {
        float tv = c * w_ce1[j] + b_ce1[j];
        tv = tv / (1.0f + __expf(-tv)); // silu
        acc += tv * w_ce2[j * 16 + h];
    }
    biasbuf[((size_t)b * 16 + h) * 2048 + n] = gbuf[b] * acc;
}

// ---------------------------------------------------------------------------
// QKV GEMM: qkv[r][c] = sum_k X[r][k] * Wt[c][k]; scatter into Q,K (b,h,n,hd)
// and Vt (b,h,hd,n). Block = 4 waves, wave tile 16(M) x 64(N).
__global__ __launch_bounds__(256) void qkv_gemm(const bf16_t* __restrict__ X,
                                                const bf16_t* __restrict__ Wt,
                                                bf16_t* __restrict__ Q,
                                                bf16_t* __restrict__ Kb,
                                                bf16_t* __restrict__ Vt) {
    int w = threadIdx.x >> 6, lane = threadIdx.x & 63;
    int l16 = lane & 15, quad = lane >> 4;
    int m0 = blockIdx.y * 64 + w * 16;
    int n0 = blockIdx.x * 64;
    const bf16_t* arow = X + (size_t)(m0 + l16) * 1024 + quad * 8;
    const bf16_t* brow = Wt + (size_t)(n0 + l16) * 1024 + quad * 8;
    f32x4 acc[4] = {};
    for (int k = 0; k < 1024; k += 32) {
        bf16x8 a = *(const bf16x8*)(arow + k);
#pragma unroll
        for (int cc = 0; cc < 4; ++cc) {
            bf16x8 bb = *(const bf16x8*)(brow + (size_t)cc * 16 * 1024 + k);
            acc[cc] = MFMA16(a, bb, acc[cc]);
        }
    }
#pragma unroll
    for (int cc = 0; cc < 4; ++cc) {
        int col = n0 + cc * 16 + l16;
        int sec = col >> 10;       // 0=q 1=k 2=v
        int dcol = col & 1023;
        int h = dcol >> 6, hd = dcol & 63;
#pragma unroll
        for (int r = 0; r < 4; ++r) {
            int row = m0 + quad * 4 + r;
            int b = row >> 11, n = row & 2047;
            bf16_t v = (bf16_t)acc[cc][r];
            size_t bh = (size_t)(b * 16 + h);
            if (sec == 0)      Q[(bh * 2048 + n) * 64 + hd] = v;
            else if (sec == 1) Kb[(bh * 2048 + n) * 64 + hd] = v;
            else               Vt[(bh * 64 + hd) * 2048 + n] = v;
        }
    }
}

// ---------------------------------------------------------------------------
// Flash attention. Block = 4 waves, each wave: 16 queries of one (b,h).
// Key tiles of 32. P transposed C-layout -> A-layout via per-wave LDS.
__global__ __launch_bounds__(256) void attn_k(const bf16_t* __restrict__ Q,
                                              const bf16_t* __restrict__ Kb,
                                              const bf16_t* __restrict__ Vt,
                                              const float* __restrict__ biasbuf,
                                              bf16_t* __restrict__ O) {
    __shared__ __align__(16) bf16_t plds[4][16 * 32];
    int w = threadIdx.x >> 6, lane = threadIdx.x & 63;
    int l16 = lane & 15, quad = lane >> 4;
    int bh = blockIdx.y;
    int b = bh >> 4, h = bh & 15;
    int q0 = blockIdx.x * 64 + w * 16;
    const bf16_t* Qh = Q + (size_t)bh * 2048 * 64;
    const bf16_t* Kh = Kb + (size_t)bh * 2048 * 64;
    const bf16_t* Vh = Vt + (size_t)bh * 64 * 2048;
    const float* bih = biasbuf + (size_t)bh * 2048;

    bf16x8 aq0 = *(const bf16x8*)(Qh + (size_t)(q0 + l16) * 64 + quad * 8);
    bf16x8 aq1 = *(const bf16x8*)(Qh + (size_t)(q0 + l16) * 64 + 32 + quad * 8);

    float mrow[4], lrow[4];
    f32x4 o[4] = {};
#pragma unroll
    for (int r = 0; r < 4; ++r) { mrow[r] = -INFINITY; lrow[r] = 0.f; }

    bf16_t* pw = &plds[w][0];

    for (int j0 = 0; j0 < 2048; j0 += 32) {
        f32x4 s0 = {}, s1 = {};
        bf16x8 k00 = *(const bf16x8*)(Kh + (size_t)(j0 + l16) * 64 + quad * 8);
        bf16x8 k01 = *(const bf16x8*)(Kh + (size_t)(j0 + l16) * 64 + 32 + quad * 8);
        bf16x8 k10 = *(const bf16x8*)(Kh + (size_t)(j0 + 16 + l16) * 64 + quad * 8);
        bf16x8 k11 = *(const bf16x8*)(Kh + (size_t)(j0 + 16 + l16) * 64 + 32 + quad * 8);
        s0 = MFMA16(aq0, k00, s0);
        s0 = MFMA16(aq1, k01, s0);
        s1 = MFMA16(aq0, k10, s1);
        s1 = MFMA16(aq1, k11, s1);

        float bias0 = bih[j0 + l16];
        float bias1 = bih[j0 + 16 + l16];
        float p0[4], p1[4], alpha[4];
#pragma unroll
        for (int r = 0; r < 4; ++r) {
            float v0 = s0[r] * SCALE + bias0;
            float v1 = s1[r] * SCALE + bias1;
            float mx = fmaxf(v0, v1);
            mx = fmaxf(mx, __shfl_xor(mx, 8));
            mx = fmaxf(mx, __shfl_xor(mx, 4));
            mx = fmaxf(mx, __shfl_xor(mx, 2));
            mx = fmaxf(mx, __shfl_xor(mx, 1));
            float mnew = fmaxf(mrow[r], mx);
            alpha[r] = __expf(mrow[r] - mnew);
            p0[r] = __expf(v0 - mnew);
            p1[r] = __expf(v1 - mnew);
            float rs = p0[r] + p1[r];
            rs += __shfl_xor(rs, 8);
            rs += __shfl_xor(rs, 4);
            rs += __shfl_xor(rs, 2);
            rs += __shfl_xor(rs, 1);
            lrow[r] = lrow[r] * alpha[r] + rs;
            mrow[r] = mnew;
        }
#pragma unroll
        for (int dt = 0; dt < 4; ++dt)
#pragma unroll
            for (int r = 0; r < 4; ++r) o[dt][r] *= alpha[r];

        // C-layout (col=key=l16, row=quad*4+r) -> LDS P[m][key]
#pragma unroll
        for (int r = 0; r < 4; ++r) {
            pw[(quad * 4 + r) * 32 + l16] = (bf16_t)p0[r];
            pw[(quad * 4 + r) * 32 + 16 + l16] = (bf16_t)p1[r];
        }
        asm volatile("s_waitcnt lgkmcnt(0)" ::: "memory");
        // A-layout read: A[m=l16][k=quad*8+i]
        bf16x8 ap = *(const bf16x8*)(pw + l16 * 32 + quad * 8);
#pragma unroll
        for (int dt = 0; dt < 4; ++dt) {
            bf16x8 bv = *(const bf16x8*)(Vh + (size_t)(dt * 16 + l16) * 2048 + j0 + quad * 8);
            o[dt] = MFMA16(ap, bv, o[dt]);
        }
    }
#pragma unroll
    for (int r = 0; r < 4; ++r) lrow[r] = 1.0f / lrow[r];
#pragma unroll
    for (int dt = 0; dt < 4; ++dt)
#pragma unroll
        for (int r = 0; r < 4; ++r) {
            int row = q0 + quad * 4 + r;
            int col = h * 64 + dt * 16 + l16;
            O[(size_t)(b * 2048 + row) * 1024 + col] = (bf16_t)(o[dt][r] * lrow[r]);
        }
}

// ---------------------------------------------------------------------------
// Output GEMM: out[r][c] = sum_k O[r][k] * WoT[c][k] + b_out[c]  (fp32 out)
__global__ __launch_bounds__(256) void out_gemm(const bf16_t* __restrict__ A,
                                                const bf16_t* __restrict__ Wt,
                                                const float* __restrict__ bias,
                                                float* __restrict__ Cout) {
    int w = threadIdx.x >> 6, lane = threadIdx.x & 63;
    int l16 = lane & 15, quad = lane >> 4;
    int m0 = blockIdx.y * 64 + w * 16;
    int n0 = blockIdx.x * 64;
    const bf16_t* arow = A + (size_t)(m0 + l16) * 1024 + quad * 8;
    const bf16_t* brow = Wt + (size_t)(n0 + l16) * 1024 + quad * 8;
    f32x4 acc[4] = {};
    for (int k = 0; k < 1024; k += 32) {
        bf16x8 a = *(const bf16x8*)(arow + k);
#pragma unroll
        for (int cc = 0; cc < 4; ++cc) {
            bf16x8 bb = *(const bf16x8*)(brow + (size_t)cc * 16 * 1024 + k);
            acc[cc] = MFMA16(a, bb, acc[cc]);
        }
    }
#pragma unroll
    for (int cc = 0; cc < 4; ++cc) {
        int col = n0 + cc * 16 + l16;
        float bv = bias[col];
#pragma unroll
        for (int r = 0; r < 4; ++r) {
            int row = m0 + quad * 4 + r;
            Cout[(size_t)row * 1024 + col] = acc[cc][r] + bv;
        }
    }
}

// ---------------------------------------------------------------------------
extern "C" void kernel_launch(void* const* d_in, const int* in_sizes, int n_in,
                              void* d_out, int out_size, void* d_ws, size_t ws_size,
                              hipStream_t stream) {
    const float* x     = (const float*)d_in[0];
    const float* cov   = (const float*)d_in[1];
    const float* w_qkv = (const float*)d_in[2];
    const float* w_out = (const float*)d_in[3];
    const float* b_out = (const float*)d_in[4];
    const float* w_ce1 = (const float*)d_in[5];
    const float* b_ce1 = (const float*)d_in[6];
    const float* w_ce2 = (const float*)d_in[7];
    const float* b_ce2 = (const float*)d_in[8];
    const float* w_fg1 = (const float*)d_in[9];
    const float* b_fg1 = (const float*)d_in[10];
    const float* w_fg2 = (const float*)d_in[11];
    const float* b_fg2 = (const float*)d_in[12];

    char* ws = (char*)d_ws;
    bf16_t* Wt     = (bf16_t*)(ws);              // 3072x1024 bf16 = 6291456 B
    bf16_t* WoT    = (bf16_t*)(ws + 6291456);    // 1024x1024 bf16 = 2097152 B
    bf16_t* Xb     = (bf16_t*)(ws + 8388608);    // 4096x1024 bf16 = 8388608 B
    bf16_t* Qb     = (bf16_t*)(ws + 16777216);   // (2,16,2048,64)
    bf16_t* Kb     = (bf16_t*)(ws + 25165824);   // (2,16,2048,64)
    bf16_t* Vt     = (bf16_t*)(ws + 33554432);   // (2,16,64,2048)
    bf16_t* Ob     = (bf16_t*)(ws + 41943040);   // (4096,1024)
    float*  pooled = (float*)(ws + 50331648);    // 2x1024 f32
    float*  gbuf   = (float*)(ws + 50339840);    // 2 f32
    float*  biasb  = (float*)(ws + 50340096);    // 2x16x2048 f32

    hipMemsetAsync(pooled, 0, 2 * 1024 * sizeof(float), stream);
    f2b<<<4096, 256, 0, stream>>>(x, Xb);
    tr64<<<dim3(48, 16), 256, 0, stream>>>(w_qkv, Wt, 1024, 3072);
    tr64<<<dim3(16, 16), 256, 0, stream>>>(w_out, WoT, 1024, 1024);
    pool_partial<<<64, 256, 0, stream>>>(x, pooled);
    gate_k<<<2, 256, 0, stream>>>(pooled, w_fg1, b_fg1, w_fg2, b_fg2, gbuf);
    covbias_k<<<256, 256, 0, stream>>>(cov, w_ce1, b_ce1, w_ce2, b_ce2, gbuf, biasb);
    qkv_gemm<<<dim3(48, 64), 256, 0, stream>>>(Xb, Wt, Qb, Kb, Vt);
    attn_k<<<dim3(32, 32), 256, 0, stream>>>(Qb, Kb, Vt, biasb, Ob);
    out_gemm<<<dim3(16, 64), 256, 0, stream>>>(Ob, WoT, b_out, (float*)d_out);
}

// Round 3
// 392.098 us; speedup vs baseline: 1.7939x; 1.7939x over previous
//
#include <hip/hip_runtime.h>
#include <math.h>

typedef __bf16 bf16_t;
typedef __bf16 bf16x8 __attribute__((ext_vector_type(8)));
typedef __bf16 bf16x4 __attribute__((ext_vector_type(4)));
typedef float f32x4 __attribute__((ext_vector_type(4)));

#define MFMA16(a, b, c) __builtin_amdgcn_mfma_f32_16x16x32_bf16((a), (b), (c), 0, 0, 0)

constexpr int Bc = 2, Nc = 2048, Dc = 1024, Hc = 16, HDc = 64;
constexpr float C1 = 0.18033688011112042f;     // 0.125 * log2(e)
constexpr float LOG2E = 1.4426950408889634f;

// async global->LDS, 16B per lane; l must be wave-uniform base (HW adds lane*16)
__device__ __forceinline__ void glds16(const bf16_t* g, bf16_t* l) {
    __builtin_amdgcn_global_load_lds(
        (const __attribute__((address_space(1))) unsigned int*)g,
        (__attribute__((address_space(3))) unsigned int*)l, 16, 0, 0);
}

// ---------------------------------------------------------------------------
__global__ __launch_bounds__(256) void f2b(const float* __restrict__ src,
                                           bf16_t* __restrict__ dst) {
    int i = (blockIdx.x * 256 + threadIdx.x) * 4;
    float4 v = *(const float4*)(src + i);
    bf16x4 o = { (bf16_t)v.x, (bf16_t)v.y, (bf16_t)v.z, (bf16_t)v.w };
    *(bf16x4*)(dst + i) = o;
}

// ---------------------------------------------------------------------------
__global__ __launch_bounds__(256) void tr64(const float* __restrict__ src,
                                            bf16_t* __restrict__ dst, int R, int C) {
    __shared__ bf16_t tile[64 * 66];
    int r0 = blockIdx.y * 64, c0 = blockIdx.x * 64;
    int t = threadIdx.x;
    int cl = t & 63, rl = t >> 6;
#pragma unroll
    for (int p = 0; p < 16; ++p) {
        int r = p * 4 + rl;
        tile[r * 66 + cl] = (bf16_t)src[(size_t)(r0 + r) * C + c0 + cl];
    }
    __syncthreads();
#pragma unroll
    for (int p = 0; p < 16; ++p) {
        int r = p * 4 + rl;
        dst[(size_t)(c0 + r) * R + r0 + cl] = tile[cl * 66 + r];
    }
}

// ---------------------------------------------------------------------------
__global__ __launch_bounds__(256) void pool_partial(const float* __restrict__ x,
                                                    float* __restrict__ pooled) {
    int blk = blockIdx.x;
    int b = blk >> 5, ch = blk & 31;
    int t = threadIdx.x;
    int c = t * 4;
    float s0 = 0.f, s1 = 0.f, s2 = 0.f, s3 = 0.f;
    for (int rr = 0; rr < 64; ++rr) {
        float4 v = *(const float4*)(x + (size_t)(b * Nc + ch * 64 + rr) * Dc + c);
        s0 += v.x; s1 += v.y; s2 += v.z; s3 += v.w;
    }
    atomicAdd(&pooled[b * Dc + c + 0], s0);
    atomicAdd(&pooled[b * Dc + c + 1], s1);
    atomicAdd(&pooled[b * Dc + c + 2], s2);
    atomicAdd(&pooled[b * Dc + c + 3], s3);
}

// ---------------------------------------------------------------------------
__global__ __launch_bounds__(256) void gate_k(const float* __restrict__ pooled,
                                              const float* __restrict__ w_fg1,
                                              const float* __restrict__ b_fg1,
                                              const float* __restrict__ w_fg2,
                                              const float* __restrict__ b_fg2,
                                              float* __restrict__ gbuf) {
    int b = blockIdx.x, j = threadIdx.x;
    const float inv_n = 1.0f / 2048.0f;
    float hj = b_fg1[j];
    for (int d = 0; d < 1024; ++d)
        hj += (pooled[b * 1024 + d] * inv_n) * w_fg1[d * 256 + j];
    hj = hj / (1.0f + __expf(-hj));
    __shared__ float red[256];
    red[j] = hj * w_fg2[j];
    __syncthreads();
    for (int s = 128; s > 0; s >>= 1) {
        if (j < s) red[j] += red[j + s];
        __syncthreads();
    }
    if (j == 0) {
        float z = red[0] + b_fg2[0];
        gbuf[b] = 1.0f / (1.0f + __expf(-z));
    }
}

// ---------------------------------------------------------------------------
// biasbuf[b][h][n] = log2(e) * g[b] * (silu(cov*w_ce1+b_ce1) @ w_ce2 + b_ce2)
__global__ __launch_bounds__(256) void covbias_k(const float* __restrict__ coverage,
                                                 const float* __restrict__ w_ce1,
                                                 const float* __restrict__ b_ce1,
                                                 const float* __restrict__ w_ce2,
                                                 const float* __restrict__ b_ce2,
                                                 const float* __restrict__ gbuf,
                                                 float* __restrict__ biasbuf) {
    int t = threadIdx.x;
    int h = t & 15;
    int gn = blockIdx.x * 16 + (t >> 4);
    int b = gn >> 11, n = gn & 2047;
    float c = coverage[gn];
    float acc = b_ce2[h];
    for (int j = 0; j < 256; ++j) {
        float tv = c * w_ce1[j] + b_ce1[j];
        tv = tv / (1.0f + __expf(-tv));
        acc += tv * w_ce2[j * 16 + h];
    }
    biasbuf[((size_t)b * 16 + h) * 2048 + n] = LOG2E * gbuf[b] * acc;
}

// ---------------------------------------------------------------------------
// QKV GEMM, transposed orientation: D[m=ncol][n=xrow] = Wt-row . X-row.
// 128x128 block tile, BK=32, global_load_lds staging, XOR-swizzled LDS.
__global__ __launch_bounds__(256) void qkv_gemm(const bf16_t* __restrict__ Xb,
                                                const bf16_t* __restrict__ Wt,
                                                bf16_t* __restrict__ Q,
                                                bf16_t* __restrict__ Kb,
                                                bf16_t* __restrict__ Vt) {
    __shared__ __align__(16) bf16_t At[128 * 32]; // Wt rows (ncols)
    __shared__ __align__(16) bf16_t Bt[128 * 32]; // X rows
    int t = threadIdx.x, w = t >> 6, lane = t & 63;
    int l16 = lane & 15, quad = lane >> 4;
    int wm = w & 1, wx = w >> 1;
    int m0 = blockIdx.x * 128;  // x rows
    int n0 = blockIdx.y * 128;  // ncols (of 3072)
    f32x4 acc[4][4] = {};
    int sw = (l16 >> 2) & 3;    // read-side swizzle selector

    for (int k0 = 0; k0 < 1024; k0 += 32) {
#pragma unroll
        for (int i = 0; i < 2; ++i) {
            int fb = i * 4096 + w * 1024;        // wave-uniform byte base
            int f = fb + lane * 16;
            int row = f >> 6;
            int ch = (f >> 4) & 3;
            int sc = ch ^ ((row >> 2) & 3);
            glds16(Wt + (size_t)(n0 + row) * 1024 + k0 + sc * 8, At + (fb >> 1));
            glds16(Xb + (size_t)(m0 + row) * 1024 + k0 + sc * 8, Bt + (fb >> 1));
        }
        __syncthreads();
        bf16x8 afr[4], bfr[4];
#pragma unroll
        for (int mi = 0; mi < 4; ++mi)
            afr[mi] = *(const bf16x8*)(At + (wm * 64 + mi * 16 + l16) * 32 + ((quad ^ sw) * 8));
#pragma unroll
        for (int ni = 0; ni < 4; ++ni)
            bfr[ni] = *(const bf16x8*)(Bt + (wx * 64 + ni * 16 + l16) * 32 + ((quad ^ sw) * 8));
#pragma unroll
        for (int mi = 0; mi < 4; ++mi)
#pragma unroll
            for (int ni = 0; ni < 4; ++ni)
                acc[mi][ni] = MFMA16(afr[mi], bfr[ni], acc[mi][ni]);
        __syncthreads();
    }

    int sec = n0 >> 10; // 0=q 1=k 2=v, block-uniform
#pragma unroll
    for (int mi = 0; mi < 4; ++mi) {
        int gc = n0 + wm * 64 + mi * 16 + quad * 4;
        int dcol = gc & 1023;
        int h = dcol >> 6, hd = dcol & 63;
#pragma unroll
        for (int ni = 0; ni < 4; ++ni) {
            int gx = m0 + wx * 64 + ni * 16 + l16;
            int b = gx >> 11, n = gx & 2047;
            size_t bh = (size_t)(b * 16 + h);
            if (sec == 2) {
#pragma unroll
                for (int r = 0; r < 4; ++r)
                    Vt[(bh * 64 + hd + r) * 2048 + n] = (bf16_t)acc[mi][ni][r];
            } else {
                bf16x4 pk = { (bf16_t)acc[mi][ni][0], (bf16_t)acc[mi][ni][1],
                              (bf16_t)acc[mi][ni][2], (bf16_t)acc[mi][ni][3] };
                bf16_t* dst = (sec == 0 ? Q : Kb);
                *(bf16x4*)(dst + (bh * 2048 + n) * 64 + hd) = pk;
            }
        }
    }
}

// ---------------------------------------------------------------------------
// Flash attention v2: block = 4 waves x 32 q (128 q per block), one (b,h).
// S^T = K.Q^T trick (no LDS P round-trip), no-max exp2 softmax,
// K tiles staged in swizzled LDS shared by all waves, V direct b64 frags.
__global__ __launch_bounds__(256) void attn_k(const bf16_t* __restrict__ Q,
                                              const bf16_t* __restrict__ Kb,
                                              const bf16_t* __restrict__ Vt,
                                              const float* __restrict__ biasbuf,
                                              bf16_t* __restrict__ O) {
    __shared__ __align__(16) bf16_t kt_lds[64 * 64];
    int t = threadIdx.x, w = t >> 6, lane = t & 63;
    int l16 = lane & 15, quad = lane >> 4;
    int bh = blockIdx.y;
    int b = bh >> 4, h = bh & 15;
    int qa = blockIdx.x * 128 + w * 32;
    const bf16_t* Qh = Q + (size_t)bh * 2048 * 64;
    const bf16_t* Kh = Kb + (size_t)bh * 2048 * 64;
    const bf16_t* Vh = Vt + (size_t)bh * 64 * 2048;
    const float* bih = biasbuf + (size_t)bh * 2048;

    bf16x8 qf[2][2];
#pragma unroll
    for (int g = 0; g < 2; ++g)
#pragma unroll
        for (int dh = 0; dh < 2; ++dh)
            qf[g][dh] = *(const bf16x8*)(Qh + (size_t)(qa + g * 16 + l16) * 64 + dh * 32 + quad * 8);

    f32x4 o[2][4] = {};
    float lsum[2] = { 0.f, 0.f };
    const f32x4 zero = { 0.f, 0.f, 0.f, 0.f };

    for (int j0 = 0; j0 < 2048; j0 += 64) {
        // stage K tile [64 keys][64 d], chunk' = chunk ^ (row&7)
#pragma unroll
        for (int i = 0; i < 2; ++i) {
            int fb = i * 4096 + w * 1024;
            int f = fb + lane * 16;
            int row = f >> 7;
            int ch = (f >> 4) & 7;
            int sc = ch ^ (row & 7);
            glds16(Kh + (size_t)(j0 + row) * 64 + sc * 8, kt_lds + (fb >> 1));
        }
        __syncthreads();

        f32x4 s[4][2];
#pragma unroll
        for (int kt = 0; kt < 4; ++kt) {
            bf16x8 kf0 = *(const bf16x8*)(kt_lds + (kt * 16 + l16) * 64 + ((quad ^ (l16 & 7)) * 8));
            bf16x8 kf1 = *(const bf16x8*)(kt_lds + (kt * 16 + l16) * 64 + (((4 + quad) ^ (l16 & 7)) * 8));
            s[kt][0] = MFMA16(kf0, qf[0][0], zero);
            s[kt][0] = MFMA16(kf1, qf[0][1], s[kt][0]);
            s[kt][1] = MFMA16(kf0, qf[1][0], zero);
            s[kt][1] = MFMA16(kf1, qf[1][1], s[kt][1]);
        }

        float4 bias[4];
#pragma unroll
        for (int kt = 0; kt < 4; ++kt)
            bias[kt] = *(const float4*)(bih + j0 + kt * 16 + quad * 4);

#pragma unroll
        for (int kt = 0; kt < 4; ++kt) {
            const float* bp = (const float*)&bias[kt];
#pragma unroll
            for (int g = 0; g < 2; ++g)
#pragma unroll
                for (int r = 0; r < 4; ++r) {
                    float p = exp2f(s[kt][g][r] * C1 + bp[r]);
                    s[kt][g][r] = p;
                    lsum[g] += p;
                }
        }

        // pack P A-frags from S^T registers (key perm: k=quad*8+j -> key=pv*32+16*(j>>2)+quad*4+(j&3))
        bf16x8 pf[2][2];
#pragma unroll
        for (int g = 0; g < 2; ++g)
#pragma unroll
            for (int pv = 0; pv < 2; ++pv) {
                bf16x8 tmp;
#pragma unroll
                for (int i = 0; i < 4; ++i) {
                    tmp[i]     = (bf16_t)s[2 * pv][g][i];
                    tmp[i + 4] = (bf16_t)s[2 * pv + 1][g][i];
                }
                pf[g][pv] = tmp;
            }

#pragma unroll
        for (int dt = 0; dt < 4; ++dt) {
            const bf16_t* vrow = Vh + (size_t)(dt * 16 + l16) * 2048 + j0 + quad * 4;
#pragma unroll
            for (int pv = 0; pv < 2; ++pv) {
                bf16x4 va = *(const bf16x4*)(vrow + pv * 32);
                bf16x4 vb = *(const bf16x4*)(vrow + pv * 32 + 16);
                bf16x8 vf = __builtin_shufflevector(va, vb, 0, 1, 2, 3, 4, 5, 6, 7);
                o[0][dt] = MFMA16(pf[0][pv], vf, o[0][dt]);
                o[1][dt] = MFMA16(pf[1][pv], vf, o[1][dt]);
            }
        }
        __syncthreads();
    }

    // reduce row sums (row = l16; partials live across quads)
#pragma unroll
    for (int g = 0; g < 2; ++g) {
        lsum[g] += __shfl_xor(lsum[g], 16);
        lsum[g] += __shfl_xor(lsum[g], 32);
    }
#pragma unroll
    for (int g = 0; g < 2; ++g) {
        float rinv[4];
#pragma unroll
        for (int r = 0; r < 4; ++r)
            rinv[r] = 1.0f / __shfl(lsum[g], quad * 4 + r);
#pragma unroll
        for (int dt = 0; dt < 4; ++dt)
#pragma unroll
            for (int r = 0; r < 4; ++r) {
                int row = qa + g * 16 + quad * 4 + r;
                O[(size_t)(b * 2048 + row) * 1024 + h * 64 + dt * 16 + l16] =
                    (bf16_t)(o[g][dt][r] * rinv[r]);
            }
    }
}

// ---------------------------------------------------------------------------
// Output GEMM (transposed orientation): D[m=outcol][n=xrow], fp32 out + bias.
__global__ __launch_bounds__(256) void out_gemm(const bf16_t* __restrict__ A,
                                                const bf16_t* __restrict__ Wt,
                                                const float* __restrict__ bias,
                                                float* __restrict__ Cout) {
    __shared__ __align__(16) bf16_t At[128 * 32]; // Wt rows (outcols)
    __shared__ __align__(16) bf16_t Bt[128 * 32]; // O rows
    int t = threadIdx.x, w = t >> 6, lane = t & 63;
    int l16 = lane & 15, quad = lane >> 4;
    int wm = w & 1, wx = w >> 1;
    int m0 = blockIdx.x * 128;
    int n0 = blockIdx.y * 128;
    f32x4 acc[4][4] = {};
    int sw = (l16 >> 2) & 3;

    for (int k0 = 0; k0 < 1024; k0 += 32) {
#pragma unroll
        for (int i = 0; i < 2; ++i) {
            int fb = i * 4096 + w * 1024;
            int f = fb + lane * 16;
            int row = f >> 6;
            int ch = (f >> 4) & 3;
            int sc = ch ^ ((row >> 2) & 3);
            glds16(Wt + (size_t)(n0 + row) * 1024 + k0 + sc * 8, At + (fb >> 1));
            glds16(A + (size_t)(m0 + row) * 1024 + k0 + sc * 8, Bt + (fb >> 1));
        }
        __syncthreads();
        bf16x8 afr[4], bfr[4];
#pragma unroll
        for (int mi = 0; mi < 4; ++mi)
            afr[mi] = *(const bf16x8*)(At + (wm * 64 + mi * 16 + l16) * 32 + ((quad ^ sw) * 8));
#pragma unroll
        for (int ni = 0; ni < 4; ++ni)
            bfr[ni] = *(const bf16x8*)(Bt + (wx * 64 + ni * 16 + l16) * 32 + ((quad ^ sw) * 8));
#pragma unroll
        for (int mi = 0; mi < 4; ++mi)
#pragma unroll
            for (int ni = 0; ni < 4; ++ni)
                acc[mi][ni] = MFMA16(afr[mi], bfr[ni], acc[mi][ni]);
        __syncthreads();
    }

#pragma unroll
    for (int mi = 0; mi < 4; ++mi) {
        int gc = n0 + wm * 64 + mi * 16 + quad * 4;
        float4 bv = *(const float4*)(bias + gc);
#pragma unroll
        for (int ni = 0; ni < 4; ++ni) {
            int gx = m0 + wx * 64 + ni * 16 + l16;
            float4 ov = { acc[mi][ni][0] + bv.x, acc[mi][ni][1] + bv.y,
                          acc[mi][ni][2] + bv.z, acc[mi][ni][3] + bv.w };
            *(float4*)(Cout + (size_t)gx * 1024 + gc) = ov;
        }
    }
}

// ---------------------------------------------------------------------------
extern "C" void kernel_launch(void* const* d_in, const int* in_sizes, int n_in,
                              void* d_out, int out_size, void* d_ws, size_t ws_size,
                              hipStream_t stream) {
    const float* x     = (const float*)d_in[0];
    const float* cov   = (const float*)d_in[1];
    const float* w_qkv = (const float*)d_in[2];
    const float* w_out = (const float*)d_in[3];
    const float* b_out = (const float*)d_in[4];
    const float* w_ce1 = (const float*)d_in[5];
    const float* b_ce1 = (const float*)d_in[6];
    const float* w_ce2 = (const float*)d_in[7];
    const float* b_ce2 = (const float*)d_in[8];
    const float* w_fg1 = (const float*)d_in[9];
    const float* b_fg1 = (const float*)d_in[10];
    const float* w_fg2 = (const float*)d_in[11];
    const float* b_fg2 = (const float*)d_in[12];

    char* ws = (char*)d_ws;
    bf16_t* Wt     = (bf16_t*)(ws);              // 3072x1024
    bf16_t* WoT    = (bf16_t*)(ws + 6291456);    // 1024x1024
    bf16_t* Xb     = (bf16_t*)(ws + 8388608);    // 4096x1024
    bf16_t* Qb     = (bf16_t*)(ws + 16777216);   // (2,16,2048,64)
    bf16_t* Kbb    = (bf16_t*)(ws + 25165824);   // (2,16,2048,64)
    bf16_t* Vt     = (bf16_t*)(ws + 33554432);   // (2,16,64,2048)
    bf16_t* Ob     = (bf16_t*)(ws + 41943040);   // (4096,1024)
    float*  pooled = (float*)(ws + 50331648);    // 2x1024 f32
    float*  gbuf   = (float*)(ws + 50339840);    // 2 f32
    float*  biasb  = (float*)(ws + 50340096);    // 2x16x2048 f32

    hipMemsetAsync(pooled, 0, 2 * 1024 * sizeof(float), stream);
    f2b<<<4096, 256, 0, stream>>>(x, Xb);
    tr64<<<dim3(48, 16), 256, 0, stream>>>(w_qkv, Wt, 1024, 3072);
    tr64<<<dim3(16, 16), 256, 0, stream>>>(w_out, WoT, 1024, 1024);
    pool_partial<<<64, 256, 0, stream>>>(x, pooled);
    gate_k<<<2, 256, 0, stream>>>(pooled, w_fg1, b_fg1, w_fg2, b_fg2, gbuf);
    covbias_k<<<256, 256, 0, stream>>>(cov, w_ce1, b_ce1, w_ce2, b_ce2, gbuf, biasb);
    qkv_gemm<<<dim3(32, 24), 256, 0, stream>>>(Xb, Wt, Qb, Kbb, Vt);
    attn_k<<<dim3(16, 32), 256, 0, stream>>>(Qb, Kbb, Vt, biasb, Ob);
    out_gemm<<<dim3(32, 8), 256, 0, stream>>>(Ob, WoT, b_out, (float*)d_out);
}

// Round 4
// 307.939 us; speedup vs baseline: 2.2841x; 1.2733x over previous
//
#include <hip/hip_runtime.h>
#include <math.h>

typedef __bf16 bf16_t;
typedef __bf16 bf16x8 __attribute__((ext_vector_type(8)));
typedef __bf16 bf16x4 __attribute__((ext_vector_type(4)));
typedef float f32x4 __attribute__((ext_vector_type(4)));

#define MFMA16(a, b, c) __builtin_amdgcn_mfma_f32_16x16x32_bf16((a), (b), (c), 0, 0, 0)

constexpr int Bc = 2, Nc = 2048, Dc = 1024, Hc = 16, HDc = 64;
constexpr float C1 = 0.18033688011112042f;     // 0.125 * log2(e)
constexpr float LOG2E = 1.4426950408889634f;

// async global->LDS, 16B per lane; LDS base must be wave-uniform (HW adds lane*16)
__device__ __forceinline__ void glds16(const bf16_t* g, bf16_t* l) {
    __builtin_amdgcn_global_load_lds(
        (const __attribute__((address_space(1))) unsigned int*)g,
        (__attribute__((address_space(3))) unsigned int*)l, 16, 0, 0);
}

// ---------------------------------------------------------------------------
__global__ __launch_bounds__(256) void f2b(const float* __restrict__ src,
                                           bf16_t* __restrict__ dst) {
    int i = (blockIdx.x * 256 + threadIdx.x) * 4;
    float4 v = *(const float4*)(src + i);
    bf16x4 o = { (bf16_t)v.x, (bf16_t)v.y, (bf16_t)v.z, (bf16_t)v.w };
    *(bf16x4*)(dst + i) = o;
}

// ---------------------------------------------------------------------------
__global__ __launch_bounds__(256) void tr64(const float* __restrict__ src,
                                            bf16_t* __restrict__ dst, int R, int C) {
    __shared__ bf16_t tile[64 * 66];
    int r0 = blockIdx.y * 64, c0 = blockIdx.x * 64;
    int t = threadIdx.x;
    int cl = t & 63, rl = t >> 6;
#pragma unroll
    for (int p = 0; p < 16; ++p) {
        int r = p * 4 + rl;
        tile[r * 66 + cl] = (bf16_t)src[(size_t)(r0 + r) * C + c0 + cl];
    }
    __syncthreads();
#pragma unroll
    for (int p = 0; p < 16; ++p) {
        int r = p * 4 + rl;
        dst[(size_t)(c0 + r) * R + r0 + cl] = tile[cl * 66 + r];
    }
}

// ---------------------------------------------------------------------------
__global__ __launch_bounds__(256) void pool_partial(const float* __restrict__ x,
                                                    float* __restrict__ pooled) {
    int blk = blockIdx.x;
    int b = blk >> 5, ch = blk & 31;
    int t = threadIdx.x;
    int c = t * 4;
    float s0 = 0.f, s1 = 0.f, s2 = 0.f, s3 = 0.f;
    for (int rr = 0; rr < 64; ++rr) {
        float4 v = *(const float4*)(x + (size_t)(b * Nc + ch * 64 + rr) * Dc + c);
        s0 += v.x; s1 += v.y; s2 += v.z; s3 += v.w;
    }
    atomicAdd(&pooled[b * Dc + c + 0], s0);
    atomicAdd(&pooled[b * Dc + c + 1], s1);
    atomicAdd(&pooled[b * Dc + c + 2], s2);
    atomicAdd(&pooled[b * Dc + c + 3], s3);
}

// ---------------------------------------------------------------------------
__global__ __launch_bounds__(256) void gate_k(const float* __restrict__ pooled,
                                              const float* __restrict__ w_fg1,
                                              const float* __restrict__ b_fg1,
                                              const float* __restrict__ w_fg2,
                                              const float* __restrict__ b_fg2,
                                              float* __restrict__ gbuf) {
    int b = blockIdx.x, j = threadIdx.x;
    const float inv_n = 1.0f / 2048.0f;
    float hj = b_fg1[j];
    for (int d = 0; d < 1024; ++d)
        hj += (pooled[b * 1024 + d] * inv_n) * w_fg1[d * 256 + j];
    hj = hj / (1.0f + __expf(-hj));
    __shared__ float red[256];
    red[j] = hj * w_fg2[j];
    __syncthreads();
    for (int s = 128; s > 0; s >>= 1) {
        if (j < s) red[j] += red[j + s];
        __syncthreads();
    }
    if (j == 0) {
        float z = red[0] + b_fg2[0];
        gbuf[b] = 1.0f / (1.0f + __expf(-z));
    }
}

// ---------------------------------------------------------------------------
__global__ __launch_bounds__(256) void covbias_k(const float* __restrict__ coverage,
                                                 const float* __restrict__ w_ce1,
                                                 const float* __restrict__ b_ce1,
                                                 const float* __restrict__ w_ce2,
                                                 const float* __restrict__ b_ce2,
                                                 const float* __restrict__ gbuf,
                                                 float* __restrict__ biasbuf) {
    int t = threadIdx.x;
    int h = t & 15;
    int gn = blockIdx.x * 16 + (t >> 4);
    int b = gn >> 11, n = gn & 2047;
    float c = coverage[gn];
    float acc = b_ce2[h];
    for (int j = 0; j < 256; ++j) {
        float tv = c * w_ce1[j] + b_ce1[j];
        tv = tv / (1.0f + __expf(-tv));
        acc += tv * w_ce2[j * 16 + h];
    }
    biasbuf[((size_t)b * 16 + h) * 2048 + n] = LOG2E * gbuf[b] * acc;
}

// ---------------------------------------------------------------------------
// QKV GEMM, transposed orientation: D[m=ncol][n=xrow] = Wt-row . X-row.
__global__ __launch_bounds__(256) void qkv_gemm(const bf16_t* __restrict__ Xb,
                                                const bf16_t* __restrict__ Wt,
                                                bf16_t* __restrict__ Q,
                                                bf16_t* __restrict__ Kb,
                                                bf16_t* __restrict__ Vt) {
    __shared__ __align__(16) bf16_t At[128 * 32];
    __shared__ __align__(16) bf16_t Bt[128 * 32];
    int t = threadIdx.x, w = t >> 6, lane = t & 63;
    int l16 = lane & 15, quad = lane >> 4;
    int wm = w & 1, wx = w >> 1;
    int m0 = blockIdx.x * 128;
    int n0 = blockIdx.y * 128;
    f32x4 acc[4][4] = {};
    int sw = (l16 >> 2) & 3;

    for (int k0 = 0; k0 < 1024; k0 += 32) {
#pragma unroll
        for (int i = 0; i < 2; ++i) {
            int fb = i * 4096 + w * 1024;
            int f = fb + lane * 16;
            int row = f >> 6;
            int ch = (f >> 4) & 3;
            int sc = ch ^ ((row >> 2) & 3);
            glds16(Wt + (size_t)(n0 + row) * 1024 + k0 + sc * 8, At + (fb >> 1));
            glds16(Xb + (size_t)(m0 + row) * 1024 + k0 + sc * 8, Bt + (fb >> 1));
        }
        __syncthreads();
        bf16x8 afr[4], bfr[4];
#pragma unroll
        for (int mi = 0; mi < 4; ++mi)
            afr[mi] = *(const bf16x8*)(At + (wm * 64 + mi * 16 + l16) * 32 + ((quad ^ sw) * 8));
#pragma unroll
        for (int ni = 0; ni < 4; ++ni)
            bfr[ni] = *(const bf16x8*)(Bt + (wx * 64 + ni * 16 + l16) * 32 + ((quad ^ sw) * 8));
#pragma unroll
        for (int mi = 0; mi < 4; ++mi)
#pragma unroll
            for (int ni = 0; ni < 4; ++ni)
                acc[mi][ni] = MFMA16(afr[mi], bfr[ni], acc[mi][ni]);
        __syncthreads();
    }

    int sec = n0 >> 10;
#pragma unroll
    for (int mi = 0; mi < 4; ++mi) {
        int gc = n0 + wm * 64 + mi * 16 + quad * 4;
        int dcol = gc & 1023;
        int h = dcol >> 6, hd = dcol & 63;
#pragma unroll
        for (int ni = 0; ni < 4; ++ni) {
            int gx = m0 + wx * 64 + ni * 16 + l16;
            int b = gx >> 11, n = gx & 2047;
            size_t bh = (size_t)(b * 16 + h);
            if (sec == 2) {
#pragma unroll
                for (int r = 0; r < 4; ++r)
                    Vt[(bh * 64 + hd + r) * 2048 + n] = (bf16_t)acc[mi][ni][r];
            } else {
                bf16x4 pk = { (bf16_t)acc[mi][ni][0], (bf16_t)acc[mi][ni][1],
                              (bf16_t)acc[mi][ni][2], (bf16_t)acc[mi][ni][3] };
                bf16_t* dst = (sec == 0 ? Q : Kb);
                *(bf16x4*)(dst + (bh * 2048 + n) * 64 + hd) = pk;
            }
        }
    }
}

// ---------------------------------------------------------------------------
// Flash attention v3: 4 waves x 16 q = 64 q/block, 1024 blocks (16 waves/CU).
// S^T = K.Q^T (no LDS P round-trip), no-max exp2 softmax, K AND V tiles in
// double-buffered swizzled LDS (prefetch t+1 while computing t).
__global__ __launch_bounds__(256) void attn_k(const bf16_t* __restrict__ Q,
                                              const bf16_t* __restrict__ Kb,
                                              const bf16_t* __restrict__ Vt,
                                              const float* __restrict__ biasbuf,
                                              bf16_t* __restrict__ O) {
    __shared__ __align__(16) bf16_t kbuf[2][64 * 64];
    __shared__ __align__(16) bf16_t vbuf[2][64 * 64];
    int t = threadIdx.x, w = t >> 6, lane = t & 63;
    int l16 = lane & 15, quad = lane >> 4;
    int bh = blockIdx.y;
    int b = bh >> 4, h = bh & 15;
    int qa = blockIdx.x * 64 + w * 16;
    const bf16_t* Qh = Q + (size_t)bh * 2048 * 64;
    const bf16_t* Kh = Kb + (size_t)bh * 2048 * 64;
    const bf16_t* Vh = Vt + (size_t)bh * 64 * 2048;
    const float* bih = biasbuf + (size_t)bh * 2048;

    // staging geometry (each wave stages 2x1KB of K and of V)
    int fb0 = w * 2048, fb1 = fb0 + 1024;
    int f0 = fb0 + lane * 16, f1 = fb1 + lane * 16;
    int krow0 = f0 >> 7, kch0 = ((f0 >> 4) & 7) ^ (krow0 & 7);
    int krow1 = f1 >> 7, kch1 = ((f1 >> 4) & 7) ^ (krow1 & 7);

    bf16x8 qf[2];
#pragma unroll
    for (int dh = 0; dh < 2; ++dh)
        qf[dh] = *(const bf16x8*)(Qh + (size_t)(qa + l16) * 64 + dh * 32 + quad * 8);

    f32x4 o[4] = {};
    float lsum = 0.f;
    const f32x4 zero = { 0.f, 0.f, 0.f, 0.f };
    int swl = l16 & 7;
    int qh = quad >> 1, ql = quad & 1;

    // prefetch tile 0
    {
        glds16(Kh + (size_t)krow0 * 64 + kch0 * 8, &kbuf[0][fb0 >> 1]);
        glds16(Kh + (size_t)krow1 * 64 + kch1 * 8, &kbuf[0][fb1 >> 1]);
        glds16(Vh + (size_t)krow0 * 2048 + kch0 * 8, &vbuf[0][fb0 >> 1]);
        glds16(Vh + (size_t)krow1 * 2048 + kch1 * 8, &vbuf[0][fb1 >> 1]);
    }

    for (int it = 0; it < 32; ++it) {
        int j0 = it * 64, sel = it & 1;
        __syncthreads();
        if (it + 1 < 32) {
            int jn = j0 + 64, sn = sel ^ 1;
            glds16(Kh + (size_t)(jn + krow0) * 64 + kch0 * 8, &kbuf[sn][fb0 >> 1]);
            glds16(Kh + (size_t)(jn + krow1) * 64 + kch1 * 8, &kbuf[sn][fb1 >> 1]);
            glds16(Vh + (size_t)krow0 * 2048 + jn + kch0 * 8, &vbuf[sn][fb0 >> 1]);
            glds16(Vh + (size_t)krow1 * 2048 + jn + kch1 * 8, &vbuf[sn][fb1 >> 1]);
        }
        const bf16_t* kb = kbuf[sel];
        const bf16_t* vb = vbuf[sel];

        float4 bias[4];
#pragma unroll
        for (int kt = 0; kt < 4; ++kt)
            bias[kt] = *(const float4*)(bih + j0 + kt * 16 + quad * 4);

        f32x4 s[4];
#pragma unroll
        for (int kt = 0; kt < 4; ++kt) {
            bf16x8 kf0 = *(const bf16x8*)(kb + (kt * 16 + l16) * 64 + ((quad ^ swl) * 8));
            bf16x8 kf1 = *(const bf16x8*)(kb + (kt * 16 + l16) * 64 + (((4 + quad) ^ swl) * 8));
            s[kt] = MFMA16(kf0, qf[0], zero);
            s[kt] = MFMA16(kf1, qf[1], s[kt]);
        }

#pragma unroll
        for (int kt = 0; kt < 4; ++kt) {
            const float* bp = (const float*)&bias[kt];
#pragma unroll
            for (int r = 0; r < 4; ++r) {
                float p = exp2f(s[kt][r] * C1 + bp[r]);
                s[kt][r] = p;
                lsum += p;
            }
        }

        // pack P A-frags (key perm: k=quad*8+j -> key=pv*32+16*(j>>2)+quad*4+(j&3))
        bf16x8 pf[2];
#pragma unroll
        for (int pv = 0; pv < 2; ++pv) {
            bf16x8 tmp;
#pragma unroll
            for (int i = 0; i < 4; ++i) {
                tmp[i]     = (bf16_t)s[2 * pv][i];
                tmp[i + 4] = (bf16_t)s[2 * pv + 1][i];
            }
            pf[pv] = tmp;
        }

#pragma unroll
        for (int dt = 0; dt < 4; ++dt) {
            const bf16_t* vrow = vb + (dt * 16 + l16) * 64 + ql * 4;
#pragma unroll
            for (int pv = 0; pv < 2; ++pv) {
                int c0 = (pv * 4 + qh) ^ swl;       // jj=0 chunk
                int c1 = (pv * 4 + 2 + qh) ^ swl;   // jj=1 chunk
                bf16x4 va = *(const bf16x4*)(vrow + c0 * 8);
                bf16x4 vc = *(const bf16x4*)(vrow + c1 * 8);
                bf16x8 vf = __builtin_shufflevector(va, vc, 0, 1, 2, 3, 4, 5, 6, 7);
                o[dt] = MFMA16(pf[pv], vf, o[dt]);
            }
        }
    }

    lsum += __shfl_xor(lsum, 16);
    lsum += __shfl_xor(lsum, 32);
    float rinv[4];
#pragma unroll
    for (int r = 0; r < 4; ++r)
        rinv[r] = 1.0f / __shfl(lsum, quad * 4 + r);
#pragma unroll
    for (int dt = 0; dt < 4; ++dt)
#pragma unroll
        for (int r = 0; r < 4; ++r) {
            int row = qa + quad * 4 + r;
            O[(size_t)(b * 2048 + row) * 1024 + h * 64 + dt * 16 + l16] =
                (bf16_t)(o[dt][r] * rinv[r]);
        }
}

// ---------------------------------------------------------------------------
__global__ __launch_bounds__(256) void out_gemm(const bf16_t* __restrict__ A,
                                                const bf16_t* __restrict__ Wt,
                                                const float* __restrict__ bias,
                                                float* __restrict__ Cout) {
    __shared__ __align__(16) bf16_t At[128 * 32];
    __shared__ __align__(16) bf16_t Bt[128 * 32];
    int t = threadIdx.x, w = t >> 6, lane = t & 63;
    int l16 = lane & 15, quad = lane >> 4;
    int wm = w & 1, wx = w >> 1;
    int m0 = blockIdx.x * 128;
    int n0 = blockIdx.y * 128;
    f32x4 acc[4][4] = {};
    int sw = (l16 >> 2) & 3;

    for (int k0 = 0; k0 < 1024; k0 += 32) {
#pragma unroll
        for (int i = 0; i < 2; ++i) {
            int fb = i * 4096 + w * 1024;
            int f = fb + lane * 16;
            int row = f >> 6;
            int ch = (f >> 4) & 3;
            int sc = ch ^ ((row >> 2) & 3);
            glds16(Wt + (size_t)(n0 + row) * 1024 + k0 + sc * 8, At + (fb >> 1));
            glds16(A + (size_t)(m0 + row) * 1024 + k0 + sc * 8, Bt + (fb >> 1));
        }
        __syncthreads();
        bf16x8 afr[4], bfr[4];
#pragma unroll
        for (int mi = 0; mi < 4; ++mi)
            afr[mi] = *(const bf16x8*)(At + (wm * 64 + mi * 16 + l16) * 32 + ((quad ^ sw) * 8));
#pragma unroll
        for (int ni = 0; ni < 4; ++ni)
            bfr[ni] = *(const bf16x8*)(Bt + (wx * 64 + ni * 16 + l16) * 32 + ((quad ^ sw) * 8));
#pragma unroll
        for (int mi = 0; mi < 4; ++mi)
#pragma unroll
            for (int ni = 0; ni < 4; ++ni)
                acc[mi][ni] = MFMA16(afr[mi], bfr[ni], acc[mi][ni]);
        __syncthreads();
    }

#pragma unroll
    for (int mi = 0; mi < 4; ++mi) {
        int gc = n0 + wm * 64 + mi * 16 + quad * 4;
        float4 bv = *(const float4*)(bias + gc);
#pragma unroll
        for (int ni = 0; ni < 4; ++ni) {
            int gx = m0 + wx * 64 + ni * 16 + l16;
            float4 ov = { acc[mi][ni][0] + bv.x, acc[mi][ni][1] + bv.y,
                          acc[mi][ni][2] + bv.z, acc[mi][ni][3] + bv.w };
            *(float4*)(Cout + (size_t)gx * 1024 + gc) = ov;
        }
    }
}

// ---------------------------------------------------------------------------
extern "C" void kernel_launch(void* const* d_in, const int* in_sizes, int n_in,
                              void* d_out, int out_size, void* d_ws, size_t ws_size,
                              hipStream_t stream) {
    const float* x     = (const float*)d_in[0];
    const float* cov   = (const float*)d_in[1];
    const float* w_qkv = (const float*)d_in[2];
    const float* w_out = (const float*)d_in[3];
    const float* b_out = (const float*)d_in[4];
    const float* w_ce1 = (const float*)d_in[5];
    const float* b_ce1 = (const float*)d_in[6];
    const float* w_ce2 = (const float*)d_in[7];
    const float* b_ce2 = (const float*)d_in[8];
    const float* w_fg1 = (const float*)d_in[9];
    const float* b_fg1 = (const float*)d_in[10];
    const float* w_fg2 = (const float*)d_in[11];
    const float* b_fg2 = (const float*)d_in[12];

    char* ws = (char*)d_ws;
    bf16_t* Wt     = (bf16_t*)(ws);              // 3072x1024
    bf16_t* WoT    = (bf16_t*)(ws + 6291456);    // 1024x1024
    bf16_t* Xb     = (bf16_t*)(ws + 8388608);    // 4096x1024
    bf16_t* Qb     = (bf16_t*)(ws + 16777216);   // (2,16,2048,64)
    bf16_t* Kbb    = (bf16_t*)(ws + 25165824);   // (2,16,2048,64)
    bf16_t* Vt     = (bf16_t*)(ws + 33554432);   // (2,16,64,2048)
    bf16_t* Ob     = (bf16_t*)(ws + 41943040);   // (4096,1024)
    float*  pooled = (float*)(ws + 50331648);    // 2x1024 f32
    float*  gbuf   = (float*)(ws + 50339840);    // 2 f32
    float*  biasb  = (float*)(ws + 50340096);    // 2x16x2048 f32

    hipMemsetAsync(pooled, 0, 2 * 1024 * sizeof(float), stream);
    f2b<<<4096, 256, 0, stream>>>(x, Xb);
    tr64<<<dim3(48, 16), 256, 0, stream>>>(w_qkv, Wt, 1024, 3072);
    tr64<<<dim3(16, 16), 256, 0, stream>>>(w_out, WoT, 1024, 1024);
    pool_partial<<<64, 256, 0, stream>>>(x, pooled);
    gate_k<<<2, 256, 0, stream>>>(pooled, w_fg1, b_fg1, w_fg2, b_fg2, gbuf);
    covbias_k<<<256, 256, 0, stream>>>(cov, w_ce1, b_ce1, w_ce2, b_ce2, gbuf, biasb);
    qkv_gemm<<<dim3(32, 24), 256, 0, stream>>>(Xb, Wt, Qb, Kbb, Vt);
    attn_k<<<dim3(32, 32), 256, 0, stream>>>(Qb, Kbb, Vt, biasb, Ob);
    out_gemm<<<dim3(32, 8), 256, 0, stream>>>(Ob, WoT, b_out, (float*)d_out);
}

// Round 5
// 271.527 us; speedup vs baseline: 2.5904x; 1.1341x over previous
//
#include <hip/hip_runtime.h>
#include <math.h>

typedef __bf16 bf16_t;
typedef __bf16 bf16x8 __attribute__((ext_vector_type(8)));
typedef __bf16 bf16x4 __attribute__((ext_vector_type(4)));
typedef float f32x4 __attribute__((ext_vector_type(4)));

#define MFMA16(a, b, c) __builtin_amdgcn_mfma_f32_16x16x32_bf16((a), (b), (c), 0, 0, 0)

constexpr int Bc = 2, Nc = 2048, Dc = 1024, Hc = 16, HDc = 64;
constexpr float C1 = 0.18033688011112042f;     // 0.125 * log2(e)
constexpr float LOG2E = 1.4426950408889634f;

// async global->LDS, 16B per lane; LDS base must be wave-uniform (HW adds lane*16)
__device__ __forceinline__ void glds16(const bf16_t* g, bf16_t* l) {
    __builtin_amdgcn_global_load_lds(
        (const __attribute__((address_space(1))) unsigned int*)g,
        (__attribute__((address_space(3))) unsigned int*)l, 16, 0, 0);
}

// ---------------------------------------------------------------------------
__global__ __launch_bounds__(256) void f2b(const float* __restrict__ src,
                                           bf16_t* __restrict__ dst) {
    int i = (blockIdx.x * 256 + threadIdx.x) * 4;
    float4 v = *(const float4*)(src + i);
    bf16x4 o = { (bf16_t)v.x, (bf16_t)v.y, (bf16_t)v.z, (bf16_t)v.w };
    *(bf16x4*)(dst + i) = o;
}

// ---------------------------------------------------------------------------
__global__ __launch_bounds__(256) void tr64(const float* __restrict__ src,
                                            bf16_t* __restrict__ dst, int R, int C) {
    __shared__ bf16_t tile[64 * 66];
    int r0 = blockIdx.y * 64, c0 = blockIdx.x * 64;
    int t = threadIdx.x;
    int cl = t & 63, rl = t >> 6;
#pragma unroll
    for (int p = 0; p < 16; ++p) {
        int r = p * 4 + rl;
        tile[r * 66 + cl] = (bf16_t)src[(size_t)(r0 + r) * C + c0 + cl];
    }
    __syncthreads();
#pragma unroll
    for (int p = 0; p < 16; ++p) {
        int r = p * 4 + rl;
        dst[(size_t)(c0 + r) * R + r0 + cl] = tile[cl * 66 + r];
    }
}

// ---------------------------------------------------------------------------
// 256 blocks: b = blk>>7, 16 rows per block
__global__ __launch_bounds__(256) void pool_partial(const float* __restrict__ x,
                                                    float* __restrict__ pooled) {
    int blk = blockIdx.x;
    int b = blk >> 7, ch = blk & 127;
    int t = threadIdx.x;
    int c = t * 4;
    float s0 = 0.f, s1 = 0.f, s2 = 0.f, s3 = 0.f;
    for (int rr = 0; rr < 16; ++rr) {
        float4 v = *(const float4*)(x + (size_t)(b * Nc + ch * 16 + rr) * Dc + c);
        s0 += v.x; s1 += v.y; s2 += v.z; s3 += v.w;
    }
    atomicAdd(&pooled[b * Dc + c + 0], s0);
    atomicAdd(&pooled[b * Dc + c + 1], s1);
    atomicAdd(&pooled[b * Dc + c + 2], s2);
    atomicAdd(&pooled[b * Dc + c + 3], s3);
}

// ---------------------------------------------------------------------------
// Gate MLP stage 1, parallel: one block per (b, j). hacc[b] += silu(h_j)*w_fg2[j]
__global__ __launch_bounds__(256) void gate1(const float* __restrict__ pooled,
                                             const float* __restrict__ w_fg1,
                                             const float* __restrict__ b_fg1,
                                             const float* __restrict__ w_fg2,
                                             float* __restrict__ hacc) {
    int b = blockIdx.x >> 8, j = blockIdx.x & 255;
    int t = threadIdx.x;
    float p = 0.f;
#pragma unroll
    for (int i = 0; i < 4; ++i) {
        int d = t * 4 + i;
        p += pooled[b * 1024 + d] * w_fg1[d * 256 + j];
    }
#pragma unroll
    for (int off = 32; off > 0; off >>= 1) p += __shfl_down(p, off);
    __shared__ float red[4];
    if ((t & 63) == 0) red[t >> 6] = p;
    __syncthreads();
    if (t == 0) {
        float hj = (red[0] + red[1] + red[2] + red[3]) * (1.0f / 2048.0f) + b_fg1[j];
        hj = hj / (1.0f + __expf(-hj)); // silu
        atomicAdd(&hacc[b], hj * w_fg2[j]);
    }
}

// ---------------------------------------------------------------------------
// biasbuf[b][h][n] = log2(e) * sigmoid(hacc[b]+b_fg2) * (silu(cov*w_ce1+b_ce1) @ w_ce2 + b_ce2)
__global__ __launch_bounds__(256) void covbias_k(const float* __restrict__ coverage,
                                                 const float* __restrict__ w_ce1,
                                                 const float* __restrict__ b_ce1,
                                                 const float* __restrict__ w_ce2,
                                                 const float* __restrict__ b_ce2,
                                                 const float* __restrict__ hacc,
                                                 const float* __restrict__ b_fg2,
                                                 float* __restrict__ biasbuf) {
    int t = threadIdx.x;
    int h = t & 15;
    int gn = blockIdx.x * 16 + (t >> 4);
    int b = gn >> 11, n = gn & 2047;
    float g = 1.0f / (1.0f + __expf(-(hacc[b] + b_fg2[0])));
    float c = coverage[gn];
    float acc = b_ce2[h];
    for (int j = 0; j < 256; ++j) {
        float tv = c * w_ce1[j] + b_ce1[j];
        tv = tv / (1.0f + __expf(-tv));
        acc += tv * w_ce2[j * 16 + h];
    }
    biasbuf[((size_t)b * 16 + h) * 2048 + n] = LOG2E * g * acc;
}

// ---------------------------------------------------------------------------
// QKV GEMM, transposed orientation: D[m=ncol][n=xrow] = Wt-row . X-row.
__global__ __launch_bounds__(256) void qkv_gemm(const bf16_t* __restrict__ Xb,
                                                const bf16_t* __restrict__ Wt,
                                                bf16_t* __restrict__ Q,
                                                bf16_t* __restrict__ Kb,
                                                bf16_t* __restrict__ Vt) {
    __shared__ __align__(16) bf16_t At[128 * 32];
    __shared__ __align__(16) bf16_t Bt[128 * 32];
    int t = threadIdx.x, w = t >> 6, lane = t & 63;
    int l16 = lane & 15, quad = lane >> 4;
    int wm = w & 1, wx = w >> 1;
    int m0 = blockIdx.x * 128;
    int n0 = blockIdx.y * 128;
    f32x4 acc[4][4] = {};
    int sw = (l16 >> 2) & 3;

    for (int k0 = 0; k0 < 1024; k0 += 32) {
#pragma unroll
        for (int i = 0; i < 2; ++i) {
            int fb = i * 4096 + w * 1024;
            int f = fb + lane * 16;
            int row = f >> 6;
            int ch = (f >> 4) & 3;
            int sc = ch ^ ((row >> 2) & 3);
            glds16(Wt + (size_t)(n0 + row) * 1024 + k0 + sc * 8, At + (fb >> 1));
            glds16(Xb + (size_t)(m0 + row) * 1024 + k0 + sc * 8, Bt + (fb >> 1));
        }
        __syncthreads();
        bf16x8 afr[4], bfr[4];
#pragma unroll
        for (int mi = 0; mi < 4; ++mi)
            afr[mi] = *(const bf16x8*)(At + (wm * 64 + mi * 16 + l16) * 32 + ((quad ^ sw) * 8));
#pragma unroll
        for (int ni = 0; ni < 4; ++ni)
            bfr[ni] = *(const bf16x8*)(Bt + (wx * 64 + ni * 16 + l16) * 32 + ((quad ^ sw) * 8));
#pragma unroll
        for (int mi = 0; mi < 4; ++mi)
#pragma unroll
            for (int ni = 0; ni < 4; ++ni)
                acc[mi][ni] = MFMA16(afr[mi], bfr[ni], acc[mi][ni]);
        __syncthreads();
    }

    int sec = n0 >> 10;
#pragma unroll
    for (int mi = 0; mi < 4; ++mi) {
        int gc = n0 + wm * 64 + mi * 16 + quad * 4;
        int dcol = gc & 1023;
        int h = dcol >> 6, hd = dcol & 63;
#pragma unroll
        for (int ni = 0; ni < 4; ++ni) {
            int gx = m0 + wx * 64 + ni * 16 + l16;
            int b = gx >> 11, n = gx & 2047;
            size_t bh = (size_t)(b * 16 + h);
            if (sec == 2) {
#pragma unroll
                for (int r = 0; r < 4; ++r)
                    Vt[(bh * 64 + hd + r) * 2048 + n] = (bf16_t)acc[mi][ni][r];
            } else {
                bf16x4 pk = { (bf16_t)acc[mi][ni][0], (bf16_t)acc[mi][ni][1],
                              (bf16_t)acc[mi][ni][2], (bf16_t)acc[mi][ni][3] };
                bf16_t* dst = (sec == 0 ? Q : Kb);
                *(bf16x4*)(dst + (bh * 2048 + n) * 64 + hd) = pk;
            }
        }
    }
}

// ---------------------------------------------------------------------------
// Flash attention v3: 4 waves x 16 q = 64 q/block, 1024 blocks.
__global__ __launch_bounds__(256) void attn_k(const bf16_t* __restrict__ Q,
                                              const bf16_t* __restrict__ Kb,
                                              const bf16_t* __restrict__ Vt,
                                              const float* __restrict__ biasbuf,
                                              bf16_t* __restrict__ O) {
    __shared__ __align__(16) bf16_t kbuf[2][64 * 64];
    __shared__ __align__(16) bf16_t vbuf[2][64 * 64];
    int t = threadIdx.x, w = t >> 6, lane = t & 63;
    int l16 = lane & 15, quad = lane >> 4;
    int bh = blockIdx.y;
    int b = bh >> 4, h = bh & 15;
    int qa = blockIdx.x * 64 + w * 16;
    const bf16_t* Qh = Q + (size_t)bh * 2048 * 64;
    const bf16_t* Kh = Kb + (size_t)bh * 2048 * 64;
    const bf16_t* Vh = Vt + (size_t)bh * 64 * 2048;
    const float* bih = biasbuf + (size_t)bh * 2048;

    int fb0 = w * 2048, fb1 = fb0 + 1024;
    int f0 = fb0 + lane * 16, f1 = fb1 + lane * 16;
    int krow0 = f0 >> 7, kch0 = ((f0 >> 4) & 7) ^ (krow0 & 7);
    int krow1 = f1 >> 7, kch1 = ((f1 >> 4) & 7) ^ (krow1 & 7);

    bf16x8 qf[2];
#pragma unroll
    for (int dh = 0; dh < 2; ++dh)
        qf[dh] = *(const bf16x8*)(Qh + (size_t)(qa + l16) * 64 + dh * 32 + quad * 8);

    f32x4 o[4] = {};
    float lsum = 0.f;
    const f32x4 zero = { 0.f, 0.f, 0.f, 0.f };
    int swl = l16 & 7;
    int qh = quad >> 1, ql = quad & 1;

    {
        glds16(Kh + (size_t)krow0 * 64 + kch0 * 8, &kbuf[0][fb0 >> 1]);
        glds16(Kh + (size_t)krow1 * 64 + kch1 * 8, &kbuf[0][fb1 >> 1]);
        glds16(Vh + (size_t)krow0 * 2048 + kch0 * 8, &vbuf[0][fb0 >> 1]);
        glds16(Vh + (size_t)krow1 * 2048 + kch1 * 8, &vbuf[0][fb1 >> 1]);
    }

    for (int it = 0; it < 32; ++it) {
        int j0 = it * 64, sel = it & 1;
        __syncthreads();
        if (it + 1 < 32) {
            int jn = j0 + 64, sn = sel ^ 1;
            glds16(Kh + (size_t)(jn + krow0) * 64 + kch0 * 8, &kbuf[sn][fb0 >> 1]);
            glds16(Kh + (size_t)(jn + krow1) * 64 + kch1 * 8, &kbuf[sn][fb1 >> 1]);
            glds16(Vh + (size_t)krow0 * 2048 + jn + kch0 * 8, &vbuf[sn][fb0 >> 1]);
            glds16(Vh + (size_t)krow1 * 2048 + jn + kch1 * 8, &vbuf[sn][fb1 >> 1]);
        }
        const bf16_t* kb = kbuf[sel];
        const bf16_t* vb = vbuf[sel];

        float4 bias[4];
#pragma unroll
        for (int kt = 0; kt < 4; ++kt)
            bias[kt] = *(const float4*)(bih + j0 + kt * 16 + quad * 4);

        f32x4 s[4];
#pragma unroll
        for (int kt = 0; kt < 4; ++kt) {
            bf16x8 kf0 = *(const bf16x8*)(kb + (kt * 16 + l16) * 64 + ((quad ^ swl) * 8));
            bf16x8 kf1 = *(const bf16x8*)(kb + (kt * 16 + l16) * 64 + (((4 + quad) ^ swl) * 8));
            s[kt] = MFMA16(kf0, qf[0], zero);
            s[kt] = MFMA16(kf1, qf[1], s[kt]);
        }

#pragma unroll
        for (int kt = 0; kt < 4; ++kt) {
            const float* bp = (const float*)&bias[kt];
#pragma unroll
            for (int r = 0; r < 4; ++r) {
                float p = __builtin_amdgcn_exp2f(s[kt][r] * C1 + bp[r]);
                s[kt][r] = p;
                lsum += p;
            }
        }

        bf16x8 pf[2];
#pragma unroll
        for (int pv = 0; pv < 2; ++pv) {
            bf16x8 tmp;
#pragma unroll
            for (int i = 0; i < 4; ++i) {
                tmp[i]     = (bf16_t)s[2 * pv][i];
                tmp[i + 4] = (bf16_t)s[2 * pv + 1][i];
            }
            pf[pv] = tmp;
        }

#pragma unroll
        for (int dt = 0; dt < 4; ++dt) {
            const bf16_t* vrow = vb + (dt * 16 + l16) * 64 + ql * 4;
#pragma unroll
            for (int pv = 0; pv < 2; ++pv) {
                int c0 = (pv * 4 + qh) ^ swl;
                int c1 = (pv * 4 + 2 + qh) ^ swl;
                bf16x4 va = *(const bf16x4*)(vrow + c0 * 8);
                bf16x4 vc = *(const bf16x4*)(vrow + c1 * 8);
                bf16x8 vf = __builtin_shufflevector(va, vc, 0, 1, 2, 3, 4, 5, 6, 7);
                o[dt] = MFMA16(pf[pv], vf, o[dt]);
            }
        }
    }

    lsum += __shfl_xor(lsum, 16);
    lsum += __shfl_xor(lsum, 32);
    float rinv[4];
#pragma unroll
    for (int r = 0; r < 4; ++r)
        rinv[r] = 1.0f / __shfl(lsum, quad * 4 + r);
#pragma unroll
    for (int dt = 0; dt < 4; ++dt)
#pragma unroll
        for (int r = 0; r < 4; ++r) {
            int row = qa + quad * 4 + r;
            O[(size_t)(b * 2048 + row) * 1024 + h * 64 + dt * 16 + l16] =
                (bf16_t)(o[dt][r] * rinv[r]);
        }
}

// ---------------------------------------------------------------------------
__global__ __launch_bounds__(256) void out_gemm(const bf16_t* __restrict__ A,
                                                const bf16_t* __restrict__ Wt,
                                                const float* __restrict__ bias,
                                                float* __restrict__ Cout) {
    __shared__ __align__(16) bf16_t At[128 * 32];
    __shared__ __align__(16) bf16_t Bt[128 * 32];
    int t = threadIdx.x, w = t >> 6, lane = t & 63;
    int l16 = lane & 15, quad = lane >> 4;
    int wm = w & 1, wx = w >> 1;
    int m0 = blockIdx.x * 128;
    int n0 = blockIdx.y * 128;
    f32x4 acc[4][4] = {};
    int sw = (l16 >> 2) & 3;

    for (int k0 = 0; k0 < 1024; k0 += 32) {
#pragma unroll
        for (int i = 0; i < 2; ++i) {
            int fb = i * 4096 + w * 1024;
            int f = fb + lane * 16;
            int row = f >> 6;
            int ch = (f >> 4) & 3;
            int sc = ch ^ ((row >> 2) & 3);
            glds16(Wt + (size_t)(n0 + row) * 1024 + k0 + sc * 8, At + (fb >> 1));
            glds16(A + (size_t)(m0 + row) * 1024 + k0 + sc * 8, Bt + (fb >> 1));
        }
        __syncthreads();
        bf16x8 afr[4], bfr[4];
#pragma unroll
        for (int mi = 0; mi < 4; ++mi)
            afr[mi] = *(const bf16x8*)(At + (wm * 64 + mi * 16 + l16) * 32 + ((quad ^ sw) * 8));
#pragma unroll
        for (int ni = 0; ni < 4; ++ni)
            bfr[ni] = *(const bf16x8*)(Bt + (wx * 64 + ni * 16 + l16) * 32 + ((quad ^ sw) * 8));
#pragma unroll
        for (int mi = 0; mi < 4; ++mi)
#pragma unroll
            for (int ni = 0; ni < 4; ++ni)
                acc[mi][ni] = MFMA16(afr[mi], bfr[ni], acc[mi][ni]);
        __syncthreads();
    }

#pragma unroll
    for (int mi = 0; mi < 4; ++mi) {
        int gc = n0 + wm * 64 + mi * 16 + quad * 4;
        float4 bv = *(const float4*)(bias + gc);
#pragma unroll
        for (int ni = 0; ni < 4; ++ni) {
            int gx = m0 + wx * 64 + ni * 16 + l16;
            float4 ov = { acc[mi][ni][0] + bv.x, acc[mi][ni][1] + bv.y,
                          acc[mi][ni][2] + bv.z, acc[mi][ni][3] + bv.w };
            *(float4*)(Cout + (size_t)gx * 1024 + gc) = ov;
        }
    }
}

// ---------------------------------------------------------------------------
extern "C" void kernel_launch(void* const* d_in, const int* in_sizes, int n_in,
                              void* d_out, int out_size, void* d_ws, size_t ws_size,
                              hipStream_t stream) {
    const float* x     = (const float*)d_in[0];
    const float* cov   = (const float*)d_in[1];
    const float* w_qkv = (const float*)d_in[2];
    const float* w_out = (const float*)d_in[3];
    const float* b_out = (const float*)d_in[4];
    const float* w_ce1 = (const float*)d_in[5];
    const float* b_ce1 = (const float*)d_in[6];
    const float* w_ce2 = (const float*)d_in[7];
    const float* b_ce2 = (const float*)d_in[8];
    const float* w_fg1 = (const float*)d_in[9];
    const float* b_fg1 = (const float*)d_in[10];
    const float* w_fg2 = (const float*)d_in[11];
    const float* b_fg2 = (const float*)d_in[12];

    char* ws = (char*)d_ws;
    bf16_t* Wt     = (bf16_t*)(ws);              // 3072x1024
    bf16_t* WoT    = (bf16_t*)(ws + 6291456);    // 1024x1024
    bf16_t* Xb     = (bf16_t*)(ws + 8388608);    // 4096x1024
    bf16_t* Qb     = (bf16_t*)(ws + 16777216);   // (2,16,2048,64)
    bf16_t* Kbb    = (bf16_t*)(ws + 25165824);   // (2,16,2048,64)
    bf16_t* Vt     = (bf16_t*)(ws + 33554432);   // (2,16,64,2048)
    bf16_t* Ob     = (bf16_t*)(ws + 41943040);   // (4096,1024)
    float*  pooled = (float*)(ws + 50331648);    // 2x1024 f32
    float*  hacc   = (float*)(ws + 50339840);    // 2 f32
    float*  biasb  = (float*)(ws + 50340096);    // 2x16x2048 f32

    hipMemsetAsync(pooled, 0, 2 * 1024 * sizeof(float), stream);
    hipMemsetAsync(hacc, 0, 2 * sizeof(float), stream);
    f2b<<<4096, 256, 0, stream>>>(x, Xb);
    tr64<<<dim3(48, 16), 256, 0, stream>>>(w_qkv, Wt, 1024, 3072);
    tr64<<<dim3(16, 16), 256, 0, stream>>>(w_out, WoT, 1024, 1024);
    pool_partial<<<256, 256, 0, stream>>>(x, pooled);
    gate1<<<512, 256, 0, stream>>>(pooled, w_fg1, b_fg1, w_fg2, hacc);
    covbias_k<<<256, 256, 0, stream>>>(cov, w_ce1, b_ce1, w_ce2, b_ce2, hacc, b_fg2, biasb);
    qkv_gemm<<<dim3(32, 24), 256, 0, stream>>>(Xb, Wt, Qb, Kbb, Vt);
    attn_k<<<dim3(32, 32), 256, 0, stream>>>(Qb, Kbb, Vt, biasb, Ob);
    out_gemm<<<dim3(32, 8), 256, 0, stream>>>(Ob, WoT, b_out, (float*)d_out);
}